// Round 9
// baseline (3183.054 us; speedup 1.0000x reference)
//
#include <hip/hip_runtime.h>

// Problem constants: B=32, S=512, L=20, T=16, E=300, H=128, D=128, V=50000

// Raw workgroup barrier: orders LDS ops (lgkmcnt drain) but does NOT drain
// vmcnt — keeps prefetch global-loads and fire-and-forget stores in flight.
#define LDS_BARRIER() do {                                   \
    asm volatile("s_waitcnt lgkmcnt(0)" ::: "memory");       \
    __builtin_amdgcn_s_barrier();                            \
    asm volatile("" ::: "memory");                           \
  } while (0)

// Launder a pointer: makes its value opaque to the compiler so loads through
// it cannot be hoisted out of the loop (LICM) or proven loop-invariant.
// Rounds 5-7: the allocator refuses to keep 96 weight floats resident
// (VGPR_Count stuck at 88) and re-fetches Wh from L2 every step anyway; this
// kernel streams the weights DELIBERATELY, pipelined to overlap compute.
#define LAUNDER_PTR(p) asm volatile("" : "+v"(p))

// ---------------------------------------------------------------------------
// K1: sentence embedding mean.  grid = B*S blocks, 128 threads.
// ---------------------------------------------------------------------------
__global__ __launch_bounds__(128) void k_sent_mean(
    const int* __restrict__ wid, const float* __restrict__ emb,
    float* __restrict__ sent)
{
  const int bs = blockIdx.x;
  const int tid = threadIdx.x;
  const int* w = wid + (size_t)bs * 20;
  float a0 = 0.f, a1 = 0.f, a2 = 0.f;
  for (int l = 0; l < 20; ++l) {
    const float* row = emb + (size_t)w[l] * 300;
    a0 += row[tid];
    a1 += row[tid + 128];
    if (tid < 44) a2 += row[tid + 256];
  }
  const float inv = 1.0f / 20.0f;
  float* o = sent + (size_t)bs * 300;
  o[tid] = a0 * inv;
  o[tid + 128] = a1 * inv;
  if (tid < 44) o[tid + 256] = a2 * inv;
}

// ---------------------------------------------------------------------------
// K2: generic fp32 tiled GEMM.  C[M,N] = A[M,K] @ B + bias, optional relu.
// BT=true : B is (N,K) row-major -> C=A@B^T ;  BT=false: B is (K,N) -> C=A@B
// 64x64 tile, 256 threads, 4x4 micro-tile, K chunked by 64.  N % 64 == 0.
// ---------------------------------------------------------------------------
template<bool BT, int ACT>
__global__ __launch_bounds__(256) void k_gemm(
    const int M, const int N, const int K,
    const float* __restrict__ A, const int lda,
    const float* __restrict__ Bm, const int ldb,
    float* __restrict__ C, const int ldc,
    const float* __restrict__ bias)
{
  (void)N;
  __shared__ float As[64][68];
  __shared__ float Bs[64][68];
  const int tid = threadIdx.x;
  const int m0 = blockIdx.x * 64;
  const int n0 = blockIdx.y * 64;
  const int tx = tid & 15;
  const int ty = tid >> 4;
  float acc[4][4] = {};

  for (int kc = 0; kc < K; kc += 64) {
    const int kb = (K - kc < 64) ? (K - kc) : 64;
    #pragma unroll
    for (int r = 0; r < 4; ++r) {
      const int m = r * 16 + ty;
      const int k4 = tx * 4;
      float4 v = make_float4(0.f, 0.f, 0.f, 0.f);
      if (m0 + m < M) {
        const float* ap = A + (size_t)(m0 + m) * lda + kc;
        if (k4 + 4 <= kb) {
          v = *(const float4*)(ap + k4);
        } else {
          float t0 = (k4 + 0 < kb) ? ap[k4 + 0] : 0.f;
          float t1 = (k4 + 1 < kb) ? ap[k4 + 1] : 0.f;
          float t2 = (k4 + 2 < kb) ? ap[k4 + 2] : 0.f;
          float t3 = (k4 + 3 < kb) ? ap[k4 + 3] : 0.f;
          v = make_float4(t0, t1, t2, t3);
        }
      }
      *(float4*)&As[m][k4] = v;
    }
    if (BT) {
      #pragma unroll
      for (int r = 0; r < 4; ++r) {
        const int n = r * 16 + ty;
        const int k4 = tx * 4;
        float4 v = make_float4(0.f, 0.f, 0.f, 0.f);
        const float* bp = Bm + (size_t)(n0 + n) * ldb + kc;
        if (k4 + 4 <= kb) {
          v = *(const float4*)(bp + k4);
        } else {
          float t0 = (k4 + 0 < kb) ? bp[k4 + 0] : 0.f;
          float t1 = (k4 + 1 < kb) ? bp[k4 + 1] : 0.f;
          float t2 = (k4 + 2 < kb) ? bp[k4 + 2] : 0.f;
          float t3 = (k4 + 3 < kb) ? bp[k4 + 3] : 0.f;
          v = make_float4(t0, t1, t2, t3);
        }
        Bs[k4 + 0][n] = v.x;
        Bs[k4 + 1][n] = v.y;
        Bs[k4 + 2][n] = v.z;
        Bs[k4 + 3][n] = v.w;
      }
    } else {
      #pragma unroll
      for (int r = 0; r < 4; ++r) {
        const int kk = r * 16 + ty;
        const int n4 = tx * 4;
        float4 v = make_float4(0.f, 0.f, 0.f, 0.f);
        if (kk < kb) v = *(const float4*)(Bm + (size_t)(kc + kk) * ldb + n0 + n4);
        *(float4*)&Bs[kk][n4] = v;
      }
    }
    __syncthreads();
    #pragma unroll 4
    for (int kk = 0; kk < kb; ++kk) {
      const float4 bv = *(const float4*)&Bs[kk][tx * 4];
      #pragma unroll
      for (int i = 0; i < 4; ++i) {
        const float a = As[ty * 4 + i][kk];
        acc[i][0] = fmaf(a, bv.x, acc[i][0]);
        acc[i][1] = fmaf(a, bv.y, acc[i][1]);
        acc[i][2] = fmaf(a, bv.z, acc[i][2]);
        acc[i][3] = fmaf(a, bv.w, acc[i][3]);
      }
    }
    __syncthreads();
  }

  float bv4[4] = {0.f, 0.f, 0.f, 0.f};
  if (bias != nullptr) {
    #pragma unroll
    for (int j = 0; j < 4; ++j) bv4[j] = bias[n0 + tx * 4 + j];
  }
  #pragma unroll
  for (int i = 0; i < 4; ++i) {
    const int m = m0 + ty * 4 + i;
    if (m < M) {
      float4 o;
      o.x = acc[i][0] + bv4[0];
      o.y = acc[i][1] + bv4[1];
      o.z = acc[i][2] + bv4[2];
      o.w = acc[i][3] + bv4[3];
      if (ACT == 1) {
        o.x = fmaxf(o.x, 0.f); o.y = fmaxf(o.y, 0.f);
        o.z = fmaxf(o.z, 0.f); o.w = fmaxf(o.w, 0.f);
      }
      *(float4*)&C[(size_t)m * ldc + n0 + tx * 4] = o;
    }
  }
}

// ---------------------------------------------------------------------------
// K3: GRU recurrence, one block per (batch, direction).  grid = 64, 512 thr.
//
// STREAMED-WEIGHT design.  Per step:
//   issue loads of K-slice-B weights (offsets 16..31 of the lane's 32-float
//   slice; laundered so they can't be hoisted) -> FMA slice-A (regs from
//   last step) -> FMA slice-B (compiler waits on the loads) -> issue
//   slice-A reload for step i+1 (lands during gates+barrier) -> partials
//   to LDS -> barrier -> gates (tid<128) -> barrier.
// ROUND-8 BUG FIXED: slice-B offset was +64 (wrong K-quarter); it is +16.
// L2 floor: 196 KB/block/step, 8 blocks/XCD at ~4.3 TB/s -> ~820 cyc/step,
// overlapped with the 384-cyc FMA issue floor.
// Structure/math otherwise identical to the validated round-6 kernel
// (8 waves: kq=wv&3 K-quarter, rg=wv>>2 row-half; partl[4][384]; 2 barriers;
// per-accumulator K order kk=0..7 -> absmax should match r6's 0.5 exactly).
// ---------------------------------------------------------------------------
__global__ __launch_bounds__(512, 2) void k_gru(
    const float* __restrict__ gi_f, const float* __restrict__ gi_b,
    const float* __restrict__ Wh_f, const float* __restrict__ Wh_b,
    const float* __restrict__ bh_f, const float* __restrict__ bh_b,
    float* __restrict__ srep, float* __restrict__ hfin)
{
  const int dir = blockIdx.x & 1;
  const int b = blockIdx.x >> 1;
  const float* gi = (dir ? gi_b : gi_f) + (size_t)b * 512 * 384;
  const float* Wh = dir ? Wh_b : Wh_f;
  const float* bh = dir ? bh_b : bh_f;

  const int tid = threadIdx.x;
  const int wv = tid >> 6;
  const int ln = tid & 63;
  const int kq = wv & 3;          // K-quarter: h floats kq*32 .. kq*32+31
  const int rg = wv >> 2;         // row half: rows rg*192 .. rg*192+191
  const int r0 = rg * 192 + ln;   // this lane's rows: r0, r0+64, r0+128

  __shared__ __align__(16) float hlds[128];
  __shared__ float partl[4 * 384];                   // [kq][row], stride-1 rows
  __shared__ __align__(16) float gis[2][32 * 384];   // 2 x 48 KB

  // weight row base pointers (this lane's 3 rows x its 32-float K-slice)
  const float* wp0 = Wh + (size_t)r0 * 128 + kq * 32;
  const float* wp1 = wp0 + 64 * 128;
  const float* wp2 = wp0 + 128 * 128;

  const float bh0 = (kq == 0) ? bh[r0] : 0.f;
  const float bh1 = (kq == 0) ? bh[r0 + 64] : 0.f;
  const float bh2 = (kq == 0) ? bh[r0 + 128] : 0.f;

  // prologue: preload K-slice-A weights (offsets 0..15) for the first step
  float4 a0[4], a1[4], a2[4];
  #pragma unroll
  for (int kk = 0; kk < 4; ++kk) {
    a0[kk] = *(const float4*)(wp0 + kk * 4);
    a1[kk] = *(const float4*)(wp1 + kk * 4);
    a2[kk] = *(const float4*)(wp2 + kk * 4);
  }

  // prologue: stage chunk 0 synchronously (3072 float4 over 512 threads)
  {
    const int lo0 = dir ? 480 : 0;
    const float4* g4 = (const float4*)(gi + (size_t)lo0 * 384);
    float4* l4 = (float4*)gis[0];
    #pragma unroll
    for (int j = 0; j < 6; ++j) l4[j * 512 + tid] = g4[j * 512 + tid];
  }
  float hreg = 0.f;
  if (tid < 128) hlds[tid] = 0.f;
  LDS_BARRIER();

  const float4* h4q = (const float4*)hlds + kq * 8;
  float4 stg[6];

  for (int c = 0; c < 16; ++c) {
    const int buf = c & 1;
    const int lo = dir ? (480 - 32 * c) : (32 * c);
    // issue next chunk's gi loads (held in regs; consumed at chunk end)
    if (c < 15) {
      const int lon = dir ? (480 - 32 * (c + 1)) : (32 * (c + 1));
      const float4* g4 = (const float4*)(gi + (size_t)lon * 384);
      #pragma unroll
      for (int j = 0; j < 6; ++j) stg[j] = g4[j * 512 + tid];
    }

    for (int i = 0; i < 32; ++i) {
      const int sloc = dir ? (31 - i) : i;    // row within chunk
      const int seq = lo + sloc;              // absolute sequence index

      // --- issue K-slice-B weight loads (offsets 16..31); laundered so
      //     they can't be hoisted/made loop-invariant -> true per-step
      //     stream.  (r8 bug was +64 here; correct is +16.) ---
      const float* q0 = wp0; LAUNDER_PTR(q0);
      const float* q1 = wp1; LAUNDER_PTR(q1);
      const float* q2 = wp2; LAUNDER_PTR(q2);
      float4 b0[4], b1[4], b2[4];
      #pragma unroll
      for (int kk = 0; kk < 4; ++kk) {
        b0[kk] = *(const float4*)(q0 + 16 + kk * 4);
        b1[kk] = *(const float4*)(q1 + 16 + kk * 4);
        b2[kk] = *(const float4*)(q2 + 16 + kk * 4);
      }

      // --- FMA slice A (kk 0..3) ---
      float4 A0 = {0.f, 0.f, 0.f, 0.f};
      float4 A1 = {0.f, 0.f, 0.f, 0.f};
      float4 A2 = {0.f, 0.f, 0.f, 0.f};
      #pragma unroll
      for (int kk = 0; kk < 4; ++kk) {
        const float4 hv = h4q[kk];
        A0.x = fmaf(a0[kk].x, hv.x, A0.x);
        A0.y = fmaf(a0[kk].y, hv.y, A0.y);
        A0.z = fmaf(a0[kk].z, hv.z, A0.z);
        A0.w = fmaf(a0[kk].w, hv.w, A0.w);
        A1.x = fmaf(a1[kk].x, hv.x, A1.x);
        A1.y = fmaf(a1[kk].y, hv.y, A1.y);
        A1.z = fmaf(a1[kk].z, hv.z, A1.z);
        A1.w = fmaf(a1[kk].w, hv.w, A1.w);
        A2.x = fmaf(a2[kk].x, hv.x, A2.x);
        A2.y = fmaf(a2[kk].y, hv.y, A2.y);
        A2.z = fmaf(a2[kk].z, hv.z, A2.z);
        A2.w = fmaf(a2[kk].w, hv.w, A2.w);
      }
      // --- FMA slice B (kk 4..7) ---
      #pragma unroll
      for (int kk = 0; kk < 4; ++kk) {
        const float4 hv = h4q[kk + 4];
        A0.x = fmaf(b0[kk].x, hv.x, A0.x);
        A0.y = fmaf(b0[kk].y, hv.y, A0.y);
        A0.z = fmaf(b0[kk].z, hv.z, A0.z);
        A0.w = fmaf(b0[kk].w, hv.w, A0.w);
        A1.x = fmaf(b1[kk].x, hv.x, A1.x);
        A1.y = fmaf(b1[kk].y, hv.y, A1.y);
        A1.z = fmaf(b1[kk].z, hv.z, A1.z);
        A1.w = fmaf(b1[kk].w, hv.w, A1.w);
        A2.x = fmaf(b2[kk].x, hv.x, A2.x);
        A2.y = fmaf(b2[kk].y, hv.y, A2.y);
        A2.z = fmaf(b2[kk].z, hv.z, A2.z);
        A2.w = fmaf(b2[kk].w, hv.w, A2.w);
      }
      partl[kq * 384 + r0]       = (A0.x + A0.y) + (A0.z + A0.w) + bh0;
      partl[kq * 384 + r0 + 64]  = (A1.x + A1.y) + (A1.z + A1.w) + bh1;
      partl[kq * 384 + r0 + 128] = (A2.x + A2.y) + (A2.z + A2.w) + bh2;

      // --- issue slice-A reload for the NEXT step (lands during gates) ---
      const float* p0 = wp0; LAUNDER_PTR(p0);
      const float* p1 = wp1; LAUNDER_PTR(p1);
      const float* p2 = wp2; LAUNDER_PTR(p2);
      #pragma unroll
      for (int kk = 0; kk < 4; ++kk) {
        a0[kk] = *(const float4*)(p0 + kk * 4);
        a1[kk] = *(const float4*)(p1 + kk * 4);
        a2[kk] = *(const float4*)(p2 + kk * 4);
      }
      LDS_BARRIER();

      if (tid < 128) {
        const float* grow = &gis[buf][sloc * 384];
        const float ghr = (partl[tid]       + partl[384 + tid])
                        + (partl[768 + tid] + partl[1152 + tid]);
        const float ghz = (partl[tid + 128]        + partl[384 + tid + 128])
                        + (partl[768 + tid + 128]  + partl[1152 + tid + 128]);
        const float ghn = (partl[tid + 256]        + partl[384 + tid + 256])
                        + (partl[768 + tid + 256]  + partl[1152 + tid + 256]);
        const float gir = grow[tid];
        const float giz = grow[tid + 128];
        const float gin = grow[tid + 256];
        const float r = __fdividef(1.f, 1.f + __expf(-(gir + ghr)));
        const float z = __fdividef(1.f, 1.f + __expf(-(giz + ghz)));
        float an = gin + r * ghn;
        an = fminf(fmaxf(an, -15.f), 15.f);
        const float t = __expf(2.f * an);
        const float n = __fdividef(t - 1.f, t + 1.f);
        hreg = (1.f - z) * n + z * hreg;
        hlds[tid] = hreg;
        srep[((size_t)(b * 512 + seq)) * 256 + dir * 128 + tid] = hreg;
      }
      LDS_BARRIER();
    }

    // write staged next chunk into the buffer we just finished reading
    if (c < 15) {
      float4* l4 = (float4*)gis[buf ^ 1];
      #pragma unroll
      for (int j = 0; j < 6; ++j) l4[j * 512 + tid] = stg[j];
      LDS_BARRIER();
    }
  }
  if (tid < 128) hfin[(size_t)dir * 4096 + (size_t)b * 128 + tid] = hreg;
}

// ---------------------------------------------------------------------------
// K4: topic boundary diffs.  grid = B*T = 512, 256 threads.
// ---------------------------------------------------------------------------
__global__ __launch_bounds__(256) void k_topic(
    const int* __restrict__ starts, const int* __restrict__ ends,
    const float* __restrict__ srep, float* __restrict__ tmat)
{
  const int bt = blockIdx.x;
  const int b = bt >> 4;
  const int st = starts[bt], en = ends[bt];
  const int j = threadIdx.x;
  float v;
  if (j < 128) {
    const float a = (en >= 1 && en <= 512) ? srep[((size_t)(b * 512 + en - 1)) * 256 + j] : 0.f;
    const float c = (st - 1 >= 1 && st - 1 <= 512) ? srep[((size_t)(b * 512 + st - 2)) * 256 + j] : 0.f;
    v = a - c;
  } else {
    const float a = (st >= 1 && st <= 512) ? srep[((size_t)(b * 512 + st - 1)) * 256 + j] : 0.f;
    const float c = (en + 1 >= 1 && en + 1 <= 512) ? srep[((size_t)(b * 512 + en)) * 256 + j] : 0.f;
    v = a - c;
  }
  tmat[(size_t)bt * 256 + j] = v;
}

// ---------------------------------------------------------------------------
// K6: attention scores + context + assemble decoder input.  grid = B*S.
// ---------------------------------------------------------------------------
__global__ __launch_bounds__(256) void k_scores(
    const float* spart, const float* __restrict__ docp, const float* __restrict__ topp,
    const float* __restrict__ v_att, const float* __restrict__ srep,
    const float* __restrict__ docrep, const float* __restrict__ tmat,
    const int* __restrict__ s2t, float* inp)
{
  const int bs = blockIdx.x;
  const int b = bs >> 9;
  const int tid = threadIdx.x;
  const int tp = s2t[bs];
  const float* sp = spart + (size_t)bs * 512;
  const float* dp = docp + (size_t)b * 512;
  const float* tq = topp + ((size_t)(b * 16 + tp)) * 512;
  float ds = 0.f, ts = 0.f;
  #pragma unroll
  for (int r = 0; r < 2; ++r) {
    const int o = tid + r * 256;
    const float s0 = sp[o], v = v_att[o];
    ds += tanhf(s0 + dp[o]) * v;
    ts += tanhf(s0 + tq[o]) * v;
  }
  #pragma unroll
  for (int off = 32; off; off >>= 1) {
    ds += __shfl_down(ds, off);
    ts += __shfl_down(ts, off);
  }
  __shared__ float rds[4], rts[4], wsh[2];
  const int wv = tid >> 6, ln = tid & 63;
  if (ln == 0) { rds[wv] = ds; rts[wv] = ts; }
  __syncthreads();
  if (tid == 0) {
    const float D = rds[0] + rds[1] + rds[2] + rds[3];
    const float T = rts[0] + rts[1] + rts[2] + rts[3];
    const float sum = D + T;
    wsh[0] = D / sum;
    wsh[1] = T / sum;
  }
  __syncthreads();
  const float dw = wsh[0], tw = wsh[1];
  const float sr = srep[(size_t)bs * 256 + tid];
  const float ctx = dw * docrep[(size_t)b * 256 + tid]
                  + tw * tmat[((size_t)(b * 16 + tp)) * 256 + tid];
  float* op = inp + (size_t)bs * 512;
  op[tid] = sr;
  op[256 + tid] = ctx;
}

// ---------------------------------------------------------------------------
// K8: logits[bs] = dot(hbuf[bs], W2) + b2.  grid = B*S, 64 threads.
// ---------------------------------------------------------------------------
__global__ __launch_bounds__(64) void k_logits(
    const float* __restrict__ hbuf, const float* __restrict__ W2,
    const float* __restrict__ b2, float* __restrict__ out)
{
  const int bs = blockIdx.x;
  const int ln = threadIdx.x;
  const float* h = hbuf + (size_t)bs * 128;
  float a = fmaf(h[ln], W2[ln], h[ln + 64] * W2[ln + 64]);
  #pragma unroll
  for (int off = 32; off; off >>= 1) a += __shfl_down(a, off);
  if (ln == 0) out[bs] = a + b2[0];
}

// ---------------------------------------------------------------------------
extern "C" void kernel_launch(void* const* d_in, const int* in_sizes, int n_in,
                              void* d_out, int out_size, void* d_ws, size_t ws_size,
                              hipStream_t stream)
{
  (void)in_sizes; (void)n_in; (void)out_size;

  const int*   word_ids = (const int*)d_in[0];
  const int*   starts   = (const int*)d_in[1];
  const int*   ends     = (const int*)d_in[2];
  const int*   s2t      = (const int*)d_in[3];
  const float* emb      = (const float*)d_in[4];
  const float* Wi_f     = (const float*)d_in[5];
  const float* Wh_f     = (const float*)d_in[6];
  const float* bi_f     = (const float*)d_in[7];
  const float* bh_f     = (const float*)d_in[8];
  const float* Wi_b     = (const float*)d_in[9];
  const float* Wh_b     = (const float*)d_in[10];
  const float* bi_b     = (const float*)d_in[11];
  const float* bh_b     = (const float*)d_in[12];
  const float* W_att    = (const float*)d_in[13];
  const float* v_att    = (const float*)d_in[14];
  const float* W1       = (const float*)d_in[15];
  const float* b1       = (const float*)d_in[16];
  const float* W2       = (const float*)d_in[17];
  const float* b2       = (const float*)d_in[18];
  float* out = (float*)d_out;

  // Workspace layout (bytes).  Aliasing:
  //   spart/inp (33.6MB) overlays gi_f+gi_b (50.3MB, dead after k_gru)
  //   hbuf (8.4MB) overlays sent (19.7MB, dead after the gi GEMMs)
  char* ws = (char*)d_ws;
  if (ws_size < 88440832u) return;   // insufficient scratch -> fail loudly
  float* sent  = (float*)(ws + 0);          // 16384*300*4 = 19,660,800
  float* gi_f  = (float*)(ws + 19660800);   // 16384*384*4 = 25,165,824
  float* gi_b  = (float*)(ws + 44826624);   // 25,165,824
  float* srep  = (float*)(ws + 69992448);   // 16384*256*4 = 16,777,216
  float* hfin  = (float*)(ws + 86769664);   // 2*32*128*4  = 32,768  (== doc_rep flat)
  float* tmat  = (float*)(ws + 86802432);   // 32*16*256*4 = 524,288
  float* docp  = (float*)(ws + 87326720);   // 32*512*4    = 65,536
  float* topp  = (float*)(ws + 87392256);   // 512*512*4   = 1,048,576 -> end 88,440,832
  float* spart = (float*)(ws + 19660800);   // alias gi_f/gi_b
  float* hbuf  = (float*)(ws + 0);          // alias sent

  // 1) sentence means
  k_sent_mean<<<16384, 128, 0, stream>>>(word_ids, emb, sent);
  // 2) input gates (parallel over all steps): gi = sent @ Wi^T + bi
  k_gemm<true, 0><<<dim3(256, 6), 256, 0, stream>>>(16384, 384, 300, sent, 300, Wi_f, 300, gi_f, 384, bi_f);
  k_gemm<true, 0><<<dim3(256, 6), 256, 0, stream>>>(16384, 384, 300, sent, 300, Wi_b, 300, gi_b, 384, bi_b);
  // 3) bidirectional GRU recurrence -> sent_rep (B,S,2H), hfin (2,B,H)
  k_gru<<<64, 512, 0, stream>>>(gi_f, gi_b, Wh_f, Wh_b, bh_f, bh_b, srep, hfin);
  // 4) topic boundary matrix
  k_topic<<<512, 256, 0, stream>>>(starts, ends, srep, tmat);
  // 5) attention partial projections (cat@W_att split by halves of W_att rows)
  k_gemm<false, 0><<<dim3(256, 8), 256, 0, stream>>>(16384, 512, 256, srep, 256, W_att + 256 * 512, 512, spart, 512, nullptr);
  k_gemm<false, 0><<<dim3(1, 8),   256, 0, stream>>>(32,    512, 256, hfin, 256, W_att,            512, docp,  512, nullptr);
  k_gemm<false, 0><<<dim3(8, 8),   256, 0, stream>>>(512,   512, 256, tmat, 256, W_att,            512, topp,  512, nullptr);
  // 6) scores -> weights -> context -> decoder input (in-place over spart)
  k_scores<<<16384, 256, 0, stream>>>(spart, docp, topp, v_att, srep, hfin, tmat, s2t, spart);
  // 7) h = relu(inp @ W1^T + b1)
  k_gemm<true, 1><<<dim3(256, 2), 256, 0, stream>>>(16384, 128, 512, spart, 512, W1, 512, hbuf, 128, b1);
  // 8) logits
  k_logits<<<16384, 64, 0, stream>>>(hbuf, W2, b2, out);
}

// Round 11
// 2141.259 us; speedup vs baseline: 1.4865x; 1.4865x over previous
//
#include <hip/hip_runtime.h>

// Problem constants: B=32, S=512, L=20, T=16, E=300, H=128, D=128, V=50000

// Raw workgroup barrier: orders LDS ops (lgkmcnt drain) but does NOT drain
// vmcnt — keeps prefetch global-loads and fire-and-forget stores in flight.
// The "memory" clobber also pins load placement across it at compile time.
#define LDS_BARRIER() do {                                   \
    asm volatile("s_waitcnt lgkmcnt(0)" ::: "memory");       \
    __builtin_amdgcn_s_barrier();                            \
    asm volatile("" ::: "memory");                           \
  } while (0)

// ---------------------------------------------------------------------------
// K1: sentence embedding mean.  grid = B*S blocks, 128 threads.
// ---------------------------------------------------------------------------
__global__ __launch_bounds__(128) void k_sent_mean(
    const int* __restrict__ wid, const float* __restrict__ emb,
    float* __restrict__ sent)
{
  const int bs = blockIdx.x;
  const int tid = threadIdx.x;
  const int* w = wid + (size_t)bs * 20;
  float a0 = 0.f, a1 = 0.f, a2 = 0.f;
  for (int l = 0; l < 20; ++l) {
    const float* row = emb + (size_t)w[l] * 300;
    a0 += row[tid];
    a1 += row[tid + 128];
    if (tid < 44) a2 += row[tid + 256];
  }
  const float inv = 1.0f / 20.0f;
  float* o = sent + (size_t)bs * 300;
  o[tid] = a0 * inv;
  o[tid + 128] = a1 * inv;
  if (tid < 44) o[tid + 256] = a2 * inv;
}

// ---------------------------------------------------------------------------
// K2: generic fp32 tiled GEMM.  C[M,N] = A[M,K] @ B + bias, optional relu.
// BT=true : B is (N,K) row-major -> C=A@B^T ;  BT=false: B is (K,N) -> C=A@B
// 64x64 tile, 256 threads, 4x4 micro-tile, K chunked by 64.  N % 64 == 0.
// ---------------------------------------------------------------------------
template<bool BT, int ACT>
__global__ __launch_bounds__(256) void k_gemm(
    const int M, const int N, const int K,
    const float* __restrict__ A, const int lda,
    const float* __restrict__ Bm, const int ldb,
    float* __restrict__ C, const int ldc,
    const float* __restrict__ bias)
{
  (void)N;
  __shared__ float As[64][68];
  __shared__ float Bs[64][68];
  const int tid = threadIdx.x;
  const int m0 = blockIdx.x * 64;
  const int n0 = blockIdx.y * 64;
  const int tx = tid & 15;
  const int ty = tid >> 4;
  float acc[4][4] = {};

  for (int kc = 0; kc < K; kc += 64) {
    const int kb = (K - kc < 64) ? (K - kc) : 64;
    #pragma unroll
    for (int r = 0; r < 4; ++r) {
      const int m = r * 16 + ty;
      const int k4 = tx * 4;
      float4 v = make_float4(0.f, 0.f, 0.f, 0.f);
      if (m0 + m < M) {
        const float* ap = A + (size_t)(m0 + m) * lda + kc;
        if (k4 + 4 <= kb) {
          v = *(const float4*)(ap + k4);
        } else {
          float t0 = (k4 + 0 < kb) ? ap[k4 + 0] : 0.f;
          float t1 = (k4 + 1 < kb) ? ap[k4 + 1] : 0.f;
          float t2 = (k4 + 2 < kb) ? ap[k4 + 2] : 0.f;
          float t3 = (k4 + 3 < kb) ? ap[k4 + 3] : 0.f;
          v = make_float4(t0, t1, t2, t3);
        }
      }
      *(float4*)&As[m][k4] = v;
    }
    if (BT) {
      #pragma unroll
      for (int r = 0; r < 4; ++r) {
        const int n = r * 16 + ty;
        const int k4 = tx * 4;
        float4 v = make_float4(0.f, 0.f, 0.f, 0.f);
        const float* bp = Bm + (size_t)(n0 + n) * ldb + kc;
        if (k4 + 4 <= kb) {
          v = *(const float4*)(bp + k4);
        } else {
          float t0 = (k4 + 0 < kb) ? bp[k4 + 0] : 0.f;
          float t1 = (k4 + 1 < kb) ? bp[k4 + 1] : 0.f;
          float t2 = (k4 + 2 < kb) ? bp[k4 + 2] : 0.f;
          float t3 = (k4 + 3 < kb) ? bp[k4 + 3] : 0.f;
          v = make_float4(t0, t1, t2, t3);
        }
        Bs[k4 + 0][n] = v.x;
        Bs[k4 + 1][n] = v.y;
        Bs[k4 + 2][n] = v.z;
        Bs[k4 + 3][n] = v.w;
      }
    } else {
      #pragma unroll
      for (int r = 0; r < 4; ++r) {
        const int kk = r * 16 + ty;
        const int n4 = tx * 4;
        float4 v = make_float4(0.f, 0.f, 0.f, 0.f);
        if (kk < kb) v = *(const float4*)(Bm + (size_t)(kc + kk) * ldb + n0 + n4);
        *(float4*)&Bs[kk][n4] = v;
      }
    }
    __syncthreads();
    #pragma unroll 4
    for (int kk = 0; kk < kb; ++kk) {
      const float4 bv = *(const float4*)&Bs[kk][tx * 4];
      #pragma unroll
      for (int i = 0; i < 4; ++i) {
        const float a = As[ty * 4 + i][kk];
        acc[i][0] = fmaf(a, bv.x, acc[i][0]);
        acc[i][1] = fmaf(a, bv.y, acc[i][1]);
        acc[i][2] = fmaf(a, bv.z, acc[i][2]);
        acc[i][3] = fmaf(a, bv.w, acc[i][3]);
      }
    }
    __syncthreads();
  }

  float bv4[4] = {0.f, 0.f, 0.f, 0.f};
  if (bias != nullptr) {
    #pragma unroll
    for (int j = 0; j < 4; ++j) bv4[j] = bias[n0 + tx * 4 + j];
  }
  #pragma unroll
  for (int i = 0; i < 4; ++i) {
    const int m = m0 + ty * 4 + i;
    if (m < M) {
      float4 o;
      o.x = acc[i][0] + bv4[0];
      o.y = acc[i][1] + bv4[1];
      o.z = acc[i][2] + bv4[2];
      o.w = acc[i][3] + bv4[3];
      if (ACT == 1) {
        o.x = fmaxf(o.x, 0.f); o.y = fmaxf(o.y, 0.f);
        o.z = fmaxf(o.z, 0.f); o.w = fmaxf(o.w, 0.f);
      }
      *(float4*)&C[(size_t)m * ldc + n0 + tx * 4] = o;
    }
  }
}

// ---------------------------------------------------------------------------
// K3: GRU recurrence, one block per (batch, direction).  grid = 64, 1024 thr.
//
// fp32 everywhere (round-10 lesson: the decoder's ds/(ds+ts) division
// amplifies srep errors ~1e4-1e6x; fp16 weights gave absmax 26.5).
//
// 16 waves; wave wv: kq = wv&7 (K-sixteenth: floats kq*16..+15),
// rg = wv>>3 (row half).  Lane owns rows r0=rg*192+ln, +64, +128 x 16 K
// = 48 weight floats (12 float4), EVEN/ODD DOUBLE-BUFFERED at source level:
// each sub-step issues the other set's 12 dwordx4 loads at its top and
// consumes them one sub-step (~2 barriers + gates) later, so the 196 KB/step
// L2 weight stream (the measured ~874-cyc wall of rounds 5-9) overlaps the
// FMA + gate phases instead of serializing.  No pointer laundering (round-9
// lesson: opaque addresses defeat alias analysis -> full serialization);
// the LDS_BARRIER asm clobbers pin load placement; only lgkmcnt drains, so
// the loads stay in flight across barriers.  If the compiler instead CSEs
// the identical loads -> true 48-VGPR residency, which is strictly better.
// partl is [8][384] (8-way K reduction, conflict-free b32 reads/writes).
// ---------------------------------------------------------------------------
__global__ __launch_bounds__(1024, 4) void k_gru(
    const float* __restrict__ gi_f, const float* __restrict__ gi_b,
    const float* __restrict__ Wh_f, const float* __restrict__ Wh_b,
    const float* __restrict__ bh_f, const float* __restrict__ bh_b,
    float* __restrict__ srep, float* __restrict__ hfin)
{
  const int dir = blockIdx.x & 1;
  const int b = blockIdx.x >> 1;
  const float* gi = (dir ? gi_b : gi_f) + (size_t)b * 512 * 384;
  const float* Wh = dir ? Wh_b : Wh_f;
  const float* bh = dir ? bh_b : bh_f;

  const int tid = threadIdx.x;
  const int wv = tid >> 6;
  const int ln = tid & 63;
  const int kq = wv & 7;          // K-sixteenth: floats kq*16 .. kq*16+15
  const int rg = wv >> 3;         // row half: rows rg*192 .. rg*192+191
  const int r0 = rg * 192 + ln;   // this lane's rows: r0, r0+64, r0+128

  __shared__ __align__(16) float hlds[128];
  __shared__ float partl[8 * 384];                   // [kq][row], stride-1 rows
  __shared__ __align__(16) float gis[2][32 * 384];   // 2 x 48 KB

  const float4* w4r0 = (const float4*)(Wh + (size_t)r0 * 128 + kq * 16);
  const float4* w4r1 = (const float4*)(Wh + (size_t)(r0 + 64) * 128 + kq * 16);
  const float4* w4r2 = (const float4*)(Wh + (size_t)(r0 + 128) * 128 + kq * 16);

  const float bh0 = (kq == 0) ? bh[r0] : 0.f;
  const float bh1 = (kq == 0) ? bh[r0 + 64] : 0.f;
  const float bh2 = (kq == 0) ? bh[r0 + 128] : 0.f;

  // double-buffered weight sets: [0..3]=row r0, [4..7]=r0+64, [8..11]=r0+128
  float4 wA[12], wB[12];
  #pragma unroll
  for (int j = 0; j < 4; ++j) {
    wA[j] = w4r0[j]; wA[4 + j] = w4r1[j]; wA[8 + j] = w4r2[j];
  }

  // prologue: stage chunk 0 synchronously (3072 float4 over 1024 threads)
  {
    const int lo0 = dir ? 480 : 0;
    const float4* g4 = (const float4*)(gi + (size_t)lo0 * 384);
    float4* l4 = (float4*)gis[0];
    #pragma unroll
    for (int j = 0; j < 3; ++j) l4[j * 1024 + tid] = g4[j * 1024 + tid];
  }
  float hreg = 0.f;
  if (tid < 128) hlds[tid] = 0.f;
  LDS_BARRIER();

  const float4* h4q = (const float4*)hlds + kq * 4;   // 4 float4 = lane's h slice
  float4 stg[3];

  // One sub-step: issue loads into OTH, compute with CUR.
#define GRU_SUBSTEP(CUR, OTH, IEXPR)                                          \
  {                                                                           \
    const int sloc = dir ? (31 - (IEXPR)) : (IEXPR);                          \
    const int seq = lo + sloc;                                                \
    _Pragma("unroll")                                                         \
    for (int j = 0; j < 4; ++j) {                                             \
      OTH[j] = w4r0[j]; OTH[4 + j] = w4r1[j]; OTH[8 + j] = w4r2[j];           \
    }                                                                         \
    float4 A0 = {0.f, 0.f, 0.f, 0.f};                                         \
    float4 A1 = {0.f, 0.f, 0.f, 0.f};                                         \
    float4 A2 = {0.f, 0.f, 0.f, 0.f};                                         \
    _Pragma("unroll")                                                         \
    for (int j = 0; j < 4; ++j) {                                             \
      const float4 hv = h4q[j];                                               \
      A0.x = fmaf(CUR[j].x, hv.x, A0.x);                                      \
      A0.y = fmaf(CUR[j].y, hv.y, A0.y);                                      \
      A0.z = fmaf(CUR[j].z, hv.z, A0.z);                                      \
      A0.w = fmaf(CUR[j].w, hv.w, A0.w);                                      \
      A1.x = fmaf(CUR[4 + j].x, hv.x, A1.x);                                  \
      A1.y = fmaf(CUR[4 + j].y, hv.y, A1.y);                                  \
      A1.z = fmaf(CUR[4 + j].z, hv.z, A1.z);                                  \
      A1.w = fmaf(CUR[4 + j].w, hv.w, A1.w);                                  \
      A2.x = fmaf(CUR[8 + j].x, hv.x, A2.x);                                  \
      A2.y = fmaf(CUR[8 + j].y, hv.y, A2.y);                                  \
      A2.z = fmaf(CUR[8 + j].z, hv.z, A2.z);                                  \
      A2.w = fmaf(CUR[8 + j].w, hv.w, A2.w);                                  \
    }                                                                         \
    partl[kq * 384 + r0]       = (A0.x + A0.y) + (A0.z + A0.w) + bh0;         \
    partl[kq * 384 + r0 + 64]  = (A1.x + A1.y) + (A1.z + A1.w) + bh1;         \
    partl[kq * 384 + r0 + 128] = (A2.x + A2.y) + (A2.z + A2.w) + bh2;         \
    LDS_BARRIER();                                                            \
    if (tid < 128) {                                                          \
      const float* grow = &gis[buf][sloc * 384];                              \
      float ghr = 0.f, ghz = 0.f, ghn = 0.f;                                  \
      _Pragma("unroll")                                                       \
      for (int q = 0; q < 8; ++q) {                                           \
        ghr += partl[q * 384 + tid];                                          \
        ghz += partl[q * 384 + tid + 128];                                    \
        ghn += partl[q * 384 + tid + 256];                                    \
      }                                                                       \
      const float gir = grow[tid];                                            \
      const float giz = grow[tid + 128];                                      \
      const float gin = grow[tid + 256];                                      \
      const float r = __fdividef(1.f, 1.f + __expf(-(gir + ghr)));            \
      const float z = __fdividef(1.f, 1.f + __expf(-(giz + ghz)));            \
      float an = gin + r * ghn;                                               \
      an = fminf(fmaxf(an, -15.f), 15.f);                                     \
      const float t = __expf(2.f * an);                                       \
      const float n = __fdividef(t - 1.f, t + 1.f);                           \
      hreg = (1.f - z) * n + z * hreg;                                        \
      hlds[tid] = hreg;                                                       \
      srep[((size_t)(b * 512 + seq)) * 256 + dir * 128 + tid] = hreg;         \
    }                                                                         \
    LDS_BARRIER();                                                            \
  }

  for (int c = 0; c < 16; ++c) {
    const int buf = c & 1;
    const int lo = dir ? (480 - 32 * c) : (32 * c);
    // issue next chunk's gi loads (held in regs; consumed at chunk end)
    if (c < 15) {
      const int lon = dir ? (480 - 32 * (c + 1)) : (32 * (c + 1));
      const float4* g4 = (const float4*)(gi + (size_t)lon * 384);
      #pragma unroll
      for (int j = 0; j < 3; ++j) stg[j] = g4[j * 1024 + tid];
    }

    for (int i = 0; i < 32; i += 2) {
      GRU_SUBSTEP(wA, wB, i);       // compute with A, prefetch B
      GRU_SUBSTEP(wB, wA, i + 1);   // compute with B, prefetch A
    }

    // write staged next chunk into the buffer we just finished reading
    if (c < 15) {
      float4* l4 = (float4*)gis[buf ^ 1];
      #pragma unroll
      for (int j = 0; j < 3; ++j) l4[j * 1024 + tid] = stg[j];
      LDS_BARRIER();
    }
  }
#undef GRU_SUBSTEP

  if (tid < 128) hfin[(size_t)dir * 4096 + (size_t)b * 128 + tid] = hreg;
}

// ---------------------------------------------------------------------------
// K4: topic boundary diffs.  grid = B*T = 512, 256 threads.
// ---------------------------------------------------------------------------
__global__ __launch_bounds__(256) void k_topic(
    const int* __restrict__ starts, const int* __restrict__ ends,
    const float* __restrict__ srep, float* __restrict__ tmat)
{
  const int bt = blockIdx.x;
  const int b = bt >> 4;
  const int st = starts[bt], en = ends[bt];
  const int j = threadIdx.x;
  float v;
  if (j < 128) {
    const float a = (en >= 1 && en <= 512) ? srep[((size_t)(b * 512 + en - 1)) * 256 + j] : 0.f;
    const float c = (st - 1 >= 1 && st - 1 <= 512) ? srep[((size_t)(b * 512 + st - 2)) * 256 + j] : 0.f;
    v = a - c;
  } else {
    const float a = (st >= 1 && st <= 512) ? srep[((size_t)(b * 512 + st - 1)) * 256 + j] : 0.f;
    const float c = (en + 1 >= 1 && en + 1 <= 512) ? srep[((size_t)(b * 512 + en)) * 256 + j] : 0.f;
    v = a - c;
  }
  tmat[(size_t)bt * 256 + j] = v;
}

// ---------------------------------------------------------------------------
// K6: attention scores + context + assemble decoder input.  grid = B*S.
// ---------------------------------------------------------------------------
__global__ __launch_bounds__(256) void k_scores(
    const float* spart, const float* __restrict__ docp, const float* __restrict__ topp,
    const float* __restrict__ v_att, const float* __restrict__ srep,
    const float* __restrict__ docrep, const float* __restrict__ tmat,
    const int* __restrict__ s2t, float* inp)
{
  const int bs = blockIdx.x;
  const int b = bs >> 9;
  const int tid = threadIdx.x;
  const int tp = s2t[bs];
  const float* sp = spart + (size_t)bs * 512;
  const float* dp = docp + (size_t)b * 512;
  const float* tq = topp + ((size_t)(b * 16 + tp)) * 512;
  float ds = 0.f, ts = 0.f;
  #pragma unroll
  for (int r = 0; r < 2; ++r) {
    const int o = tid + r * 256;
    const float s0 = sp[o], v = v_att[o];
    ds += tanhf(s0 + dp[o]) * v;
    ts += tanhf(s0 + tq[o]) * v;
  }
  #pragma unroll
  for (int off = 32; off; off >>= 1) {
    ds += __shfl_down(ds, off);
    ts += __shfl_down(ts, off);
  }
  __shared__ float rds[4], rts[4], wsh[2];
  const int wv = tid >> 6, ln = tid & 63;
  if (ln == 0) { rds[wv] = ds; rts[wv] = ts; }
  __syncthreads();
  if (tid == 0) {
    const float D = rds[0] + rds[1] + rds[2] + rds[3];
    const float T = rts[0] + rts[1] + rts[2] + rts[3];
    const float sum = D + T;
    wsh[0] = D / sum;
    wsh[1] = T / sum;
  }
  __syncthreads();
  const float dw = wsh[0], tw = wsh[1];
  const float sr = srep[(size_t)bs * 256 + tid];
  const float ctx = dw * docrep[(size_t)b * 256 + tid]
                  + tw * tmat[((size_t)(b * 16 + tp)) * 256 + tid];
  float* op = inp + (size_t)bs * 512;
  op[tid] = sr;
  op[256 + tid] = ctx;
}

// ---------------------------------------------------------------------------
// K8: logits[bs] = dot(hbuf[bs], W2) + b2.  grid = B*S, 64 threads.
// ---------------------------------------------------------------------------
__global__ __launch_bounds__(64) void k_logits(
    const float* __restrict__ hbuf, const float* __restrict__ W2,
    const float* __restrict__ b2, float* __restrict__ out)
{
  const int bs = blockIdx.x;
  const int ln = threadIdx.x;
  const float* h = hbuf + (size_t)bs * 128;
  float a = fmaf(h[ln], W2[ln], h[ln + 64] * W2[ln + 64]);
  #pragma unroll
  for (int off = 32; off; off >>= 1) a += __shfl_down(a, off);
  if (ln == 0) out[bs] = a + b2[0];
}

// ---------------------------------------------------------------------------
extern "C" void kernel_launch(void* const* d_in, const int* in_sizes, int n_in,
                              void* d_out, int out_size, void* d_ws, size_t ws_size,
                              hipStream_t stream)
{
  (void)in_sizes; (void)n_in; (void)out_size;

  const int*   word_ids = (const int*)d_in[0];
  const int*   starts   = (const int*)d_in[1];
  const int*   ends     = (const int*)d_in[2];
  const int*   s2t      = (const int*)d_in[3];
  const float* emb      = (const float*)d_in[4];
  const float* Wi_f     = (const float*)d_in[5];
  const float* Wh_f     = (const float*)d_in[6];
  const float* bi_f     = (const float*)d_in[7];
  const float* bh_f     = (const float*)d_in[8];
  const float* Wi_b     = (const float*)d_in[9];
  const float* Wh_b     = (const float*)d_in[10];
  const float* bi_b     = (const float*)d_in[11];
  const float* bh_b     = (const float*)d_in[12];
  const float* W_att    = (const float*)d_in[13];
  const float* v_att    = (const float*)d_in[14];
  const float* W1       = (const float*)d_in[15];
  const float* b1       = (const float*)d_in[16];
  const float* W2       = (const float*)d_in[17];
  const float* b2       = (const float*)d_in[18];
  float* out = (float*)d_out;

  // Workspace layout (bytes).  Aliasing:
  //   spart/inp (33.6MB) overlays gi_f+gi_b (50.3MB, dead after k_gru)
  //   hbuf (8.4MB) overlays sent (19.7MB, dead after the gi GEMMs)
  char* ws = (char*)d_ws;
  if (ws_size < 88440832u) return;   // insufficient scratch -> fail loudly
  float* sent  = (float*)(ws + 0);          // 16384*300*4 = 19,660,800
  float* gi_f  = (float*)(ws + 19660800);   // 16384*384*4 = 25,165,824
  float* gi_b  = (float*)(ws + 44826624);   // 25,165,824
  float* srep  = (float*)(ws + 69992448);   // 16384*256*4 = 16,777,216
  float* hfin  = (float*)(ws + 86769664);   // 2*32*128*4  = 32,768  (== doc_rep flat)
  float* tmat  = (float*)(ws + 86802432);   // 32*16*256*4 = 524,288
  float* docp  = (float*)(ws + 87326720);   // 32*512*4    = 65,536
  float* topp  = (float*)(ws + 87392256);   // 512*512*4   = 1,048,576 -> end 88,440,832
  float* spart = (float*)(ws + 19660800);   // alias gi_f/gi_b
  float* hbuf  = (float*)(ws + 0);          // alias sent

  // 1) sentence means
  k_sent_mean<<<16384, 128, 0, stream>>>(word_ids, emb, sent);
  // 2) input gates (parallel over all steps): gi = sent @ Wi^T + bi
  k_gemm<true, 0><<<dim3(256, 6), 256, 0, stream>>>(16384, 384, 300, sent, 300, Wi_f, 300, gi_f, 384, bi_f);
  k_gemm<true, 0><<<dim3(256, 6), 256, 0, stream>>>(16384, 384, 300, sent, 300, Wi_b, 300, gi_b, 384, bi_b);
  // 3) bidirectional GRU recurrence -> sent_rep (B,S,2H), hfin (2,B,H)
  k_gru<<<64, 1024, 0, stream>>>(gi_f, gi_b, Wh_f, Wh_b, bh_f, bh_b, srep, hfin);
  // 4) topic boundary matrix
  k_topic<<<512, 256, 0, stream>>>(starts, ends, srep, tmat);
  // 5) attention partial projections (cat@W_att split by halves of W_att rows)
  k_gemm<false, 0><<<dim3(256, 8), 256, 0, stream>>>(16384, 512, 256, srep, 256, W_att + 256 * 512, 512, spart, 512, nullptr);
  k_gemm<false, 0><<<dim3(1, 8),   256, 0, stream>>>(32,    512, 256, hfin, 256, W_att,            512, docp,  512, nullptr);
  k_gemm<false, 0><<<dim3(8, 8),   256, 0, stream>>>(512,   512, 256, tmat, 256, W_att,            512, topp,  512, nullptr);
  // 6) scores -> weights -> context -> decoder input (in-place over spart)
  k_scores<<<16384, 256, 0, stream>>>(spart, docp, topp, v_att, srep, hfin, tmat, s2t, spart);
  // 7) h = relu(inp @ W1^T + b1)
  k_gemm<true, 1><<<dim3(256, 2), 256, 0, stream>>>(16384, 128, 512, spart, 512, W1, 512, hbuf, 128, b1);
  // 8) logits
  k_logits<<<16384, 64, 0, stream>>>(hbuf, W2, b2, out);
}

// Round 12
// 710.806 us; speedup vs baseline: 4.4781x; 3.0124x over previous
//
#include <hip/hip_runtime.h>

// Problem constants: B=32, S=512, L=20, T=16, E=300, H=128, D=128, V=50000

// Raw workgroup barrier: orders LDS ops (lgkmcnt drain) but does NOT drain
// vmcnt — keeps prefetch global-loads and fire-and-forget stores in flight.
#define LDS_BARRIER() do {                                   \
    asm volatile("s_waitcnt lgkmcnt(0)" ::: "memory");       \
    __builtin_amdgcn_s_barrier();                            \
    asm volatile("" ::: "memory");                           \
  } while (0)

// ---------------------------------------------------------------------------
// K0: concatenate GRU input-gate weights/biases: Wcat (768,300) = [Wi_f;Wi_b],
// bcat (768) = [bi_f;bi_b].  grid = 450 x 256 (exactly 115200 threads).
// ---------------------------------------------------------------------------
__global__ __launch_bounds__(256) void k_wcat(
    const float* __restrict__ wf, const float* __restrict__ wb,
    const float* __restrict__ bf, const float* __restrict__ bb,
    float* __restrict__ Wcat, float* __restrict__ bcat)
{
  const int idx = blockIdx.x * 256 + threadIdx.x;   // 0 .. 115199
  Wcat[idx] = wf[idx];
  Wcat[115200 + idx] = wb[idx];
  if (idx < 384) { bcat[idx] = bf[idx]; bcat[384 + idx] = bb[idx]; }
}

// ---------------------------------------------------------------------------
// K1: sentence embedding mean, float4 loads.  grid = B*S blocks, 128 threads.
// 300 floats = 75 float4 per row; threads 0..74 each own one float4 column.
// ---------------------------------------------------------------------------
__global__ __launch_bounds__(128) void k_sent_mean(
    const int* __restrict__ wid, const float* __restrict__ emb,
    float* __restrict__ sent)
{
  const int bs = blockIdx.x;
  const int t = threadIdx.x;
  const int* w = wid + (size_t)bs * 20;
  if (t >= 75) return;
  float4 a = {0.f, 0.f, 0.f, 0.f};
  for (int l = 0; l < 20; ++l) {
    const float4 v = *(const float4*)(emb + (size_t)w[l] * 300 + t * 4);
    a.x += v.x; a.y += v.y; a.z += v.z; a.w += v.w;
  }
  const float inv = 1.0f / 20.0f;
  a.x *= inv; a.y *= inv; a.z *= inv; a.w *= inv;
  *(float4*)(sent + (size_t)bs * 300 + t * 4) = a;
}

// ---------------------------------------------------------------------------
// K2 v2: fp32 tiled GEMM with TRANSPOSED-A LDS (Ast[k][m]) so the inner loop
// is 2 x ds_read_b128 + 16 FMA per kk (v1 did 4 scalar A-reads + 1 b128 —
// LDS-instruction-bound, same disease as the round-4 GRU).
// C[M,N] = A[M,K] @ B + bias, optional relu.
// BT=true : B is (N,K) row-major -> C=A@B^T ;  BT=false: B is (K,N) -> C=A@B
// 64x64 tile, 256 threads, 4x4 micro-tile, K chunked by 64.  N % 64 == 0.
// ---------------------------------------------------------------------------
template<bool BT, int ACT>
__global__ __launch_bounds__(256) void k_gemm(
    const int M, const int N, const int K,
    const float* __restrict__ A, const int lda,
    const float* __restrict__ Bm, const int ldb,
    float* __restrict__ C, const int ldc,
    const float* __restrict__ bias)
{
  (void)N;
  __shared__ float Ast[64][68];   // [k][m] — transposed
  __shared__ float Bs[64][68];    // [k][n]
  const int tid = threadIdx.x;
  const int m0 = blockIdx.x * 64;
  const int n0 = blockIdx.y * 64;
  const int tx = tid & 15;
  const int ty = tid >> 4;
  float acc[4][4] = {};

  for (int kc = 0; kc < K; kc += 64) {
    const int kb = (K - kc < 64) ? (K - kc) : 64;
    // --- stage A tile transposed: Ast[k][m] ---
    #pragma unroll
    for (int r = 0; r < 4; ++r) {
      const int m = r * 16 + ty;
      const int k4 = tx * 4;
      float4 v = make_float4(0.f, 0.f, 0.f, 0.f);
      if (m0 + m < M) {
        const float* ap = A + (size_t)(m0 + m) * lda + kc;
        if (k4 + 4 <= kb) {
          v = *(const float4*)(ap + k4);
        } else {
          float t0 = (k4 + 0 < kb) ? ap[k4 + 0] : 0.f;
          float t1 = (k4 + 1 < kb) ? ap[k4 + 1] : 0.f;
          float t2 = (k4 + 2 < kb) ? ap[k4 + 2] : 0.f;
          float t3 = (k4 + 3 < kb) ? ap[k4 + 3] : 0.f;
          v = make_float4(t0, t1, t2, t3);
        }
      }
      Ast[k4 + 0][m] = v.x;
      Ast[k4 + 1][m] = v.y;
      Ast[k4 + 2][m] = v.z;
      Ast[k4 + 3][m] = v.w;
    }
    // --- stage B tile: Bs[k][n] ---
    if (BT) {
      #pragma unroll
      for (int r = 0; r < 4; ++r) {
        const int n = r * 16 + ty;
        const int k4 = tx * 4;
        float4 v = make_float4(0.f, 0.f, 0.f, 0.f);
        const float* bp = Bm + (size_t)(n0 + n) * ldb + kc;
        if (k4 + 4 <= kb) {
          v = *(const float4*)(bp + k4);
        } else {
          float t0 = (k4 + 0 < kb) ? bp[k4 + 0] : 0.f;
          float t1 = (k4 + 1 < kb) ? bp[k4 + 1] : 0.f;
          float t2 = (k4 + 2 < kb) ? bp[k4 + 2] : 0.f;
          float t3 = (k4 + 3 < kb) ? bp[k4 + 3] : 0.f;
          v = make_float4(t0, t1, t2, t3);
        }
        Bs[k4 + 0][n] = v.x;
        Bs[k4 + 1][n] = v.y;
        Bs[k4 + 2][n] = v.z;
        Bs[k4 + 3][n] = v.w;
      }
    } else {
      #pragma unroll
      for (int r = 0; r < 4; ++r) {
        const int kk = r * 16 + ty;
        const int n4 = tx * 4;
        float4 v = make_float4(0.f, 0.f, 0.f, 0.f);
        if (kk < kb) v = *(const float4*)(Bm + (size_t)(kc + kk) * ldb + n0 + n4);
        *(float4*)&Bs[kk][n4] = v;
      }
    }
    __syncthreads();
    #pragma unroll 4
    for (int kk = 0; kk < kb; ++kk) {
      const float4 av = *(const float4*)&Ast[kk][ty * 4];
      const float4 bv = *(const float4*)&Bs[kk][tx * 4];
      acc[0][0] = fmaf(av.x, bv.x, acc[0][0]);
      acc[0][1] = fmaf(av.x, bv.y, acc[0][1]);
      acc[0][2] = fmaf(av.x, bv.z, acc[0][2]);
      acc[0][3] = fmaf(av.x, bv.w, acc[0][3]);
      acc[1][0] = fmaf(av.y, bv.x, acc[1][0]);
      acc[1][1] = fmaf(av.y, bv.y, acc[1][1]);
      acc[1][2] = fmaf(av.y, bv.z, acc[1][2]);
      acc[1][3] = fmaf(av.y, bv.w, acc[1][3]);
      acc[2][0] = fmaf(av.z, bv.x, acc[2][0]);
      acc[2][1] = fmaf(av.z, bv.y, acc[2][1]);
      acc[2][2] = fmaf(av.z, bv.z, acc[2][2]);
      acc[2][3] = fmaf(av.z, bv.w, acc[2][3]);
      acc[3][0] = fmaf(av.w, bv.x, acc[3][0]);
      acc[3][1] = fmaf(av.w, bv.y, acc[3][1]);
      acc[3][2] = fmaf(av.w, bv.z, acc[3][2]);
      acc[3][3] = fmaf(av.w, bv.w, acc[3][3]);
    }
    __syncthreads();
  }

  float bv4[4] = {0.f, 0.f, 0.f, 0.f};
  if (bias != nullptr) {
    #pragma unroll
    for (int j = 0; j < 4; ++j) bv4[j] = bias[n0 + tx * 4 + j];
  }
  #pragma unroll
  for (int i = 0; i < 4; ++i) {
    const int m = m0 + ty * 4 + i;
    if (m < M) {
      float4 o;
      o.x = acc[i][0] + bv4[0];
      o.y = acc[i][1] + bv4[1];
      o.z = acc[i][2] + bv4[2];
      o.w = acc[i][3] + bv4[3];
      if (ACT == 1) {
        o.x = fmaxf(o.x, 0.f); o.y = fmaxf(o.y, 0.f);
        o.z = fmaxf(o.z, 0.f); o.w = fmaxf(o.w, 0.f);
      }
      *(float4*)&C[(size_t)m * ldc + n0 + tx * 4] = o;
    }
  }
}

// ---------------------------------------------------------------------------
// K3: GRU recurrence — EXACT round-6 structure (the validated 350 us / 0.5
// absmax floor; rounds 7-11 established every streaming/residency variant is
// >= this).  Only change: gi rows now have stride 768 (fused f/b gate buffer),
// this block's dir slice at column offset dir*384.
// 8 waves; wave wv: kq=wv&3 (K-quarter), rg=wv>>2 (row half); lane owns rows
// r0=rg*192+ln, +64, +128 x 32-K slice.  partl[4][384]; 2 barriers/step;
// 32-step gi chunks double-buffered via register staging.
// ---------------------------------------------------------------------------
__global__ __launch_bounds__(512, 2) void k_gru(
    const float* __restrict__ gi_fb,
    const float* __restrict__ Wh_f, const float* __restrict__ Wh_b,
    const float* __restrict__ bh_f, const float* __restrict__ bh_b,
    float* __restrict__ srep, float* __restrict__ hfin)
{
  const int dir = blockIdx.x & 1;
  const int b = blockIdx.x >> 1;
  const float* gi = gi_fb + (size_t)b * 512 * 768 + dir * 384;  // row stride 768
  const float* Wh = dir ? Wh_b : Wh_f;
  const float* bh = dir ? bh_b : bh_f;

  const int tid = threadIdx.x;
  const int wv = tid >> 6;
  const int ln = tid & 63;
  const int kq = wv & 3;          // K-quarter: h floats kq*32 .. kq*32+31
  const int rg = wv >> 2;         // row half: rows rg*192 .. rg*192+191
  const int r0 = rg * 192 + ln;   // this lane's rows: r0, r0+64, r0+128

  __shared__ __align__(16) float hlds[128];
  __shared__ float partl[4 * 384];                   // [kq][row], stride-1 rows
  __shared__ __align__(16) float gis[2][32 * 384];   // 2 x 48 KB

  // per-lane weights: 3 rows x 32-K slice = 24 float4
  float4 w0[8], w1[8], w2[8];
  {
    const float* p = Wh + (size_t)r0 * 128 + kq * 32;
    #pragma unroll
    for (int kk = 0; kk < 8; ++kk) w0[kk] = *(const float4*)(p + kk * 4);
    p += 64 * 128;
    #pragma unroll
    for (int kk = 0; kk < 8; ++kk) w1[kk] = *(const float4*)(p + kk * 4);
    p += 64 * 128;
    #pragma unroll
    for (int kk = 0; kk < 8; ++kk) w2[kk] = *(const float4*)(p + kk * 4);
  }
  const float bh0 = (kq == 0) ? bh[r0] : 0.f;
  const float bh1 = (kq == 0) ? bh[r0 + 64] : 0.f;
  const float bh2 = (kq == 0) ? bh[r0 + 128] : 0.f;

  // gi chunk staging map: flat f = j*512+tid over 3072 float4 of one chunk;
  // row = f/96 (96 float4 per 384-float dir-slice), col = f%96; global row
  // stride = 192 float4 (768 floats).
  // prologue: stage chunk 0 synchronously
  {
    const int lo0 = dir ? 480 : 0;
    const float4* g4 = (const float4*)(gi + (size_t)lo0 * 768);
    float4* l4 = (float4*)gis[0];
    #pragma unroll
    for (int j = 0; j < 6; ++j) {
      const int f = j * 512 + tid;
      const int row = f / 96;
      const int col = f - row * 96;
      l4[f] = g4[row * 192 + col];
    }
  }
  float hreg = 0.f;
  if (tid < 128) hlds[tid] = 0.f;
  LDS_BARRIER();

  const float4* h4q = (const float4*)hlds + kq * 8;
  float4 stg[6];

  for (int c = 0; c < 16; ++c) {
    const int buf = c & 1;
    const int lo = dir ? (480 - 32 * c) : (32 * c);
    // issue next chunk's gi loads (held in regs; consumed at chunk end)
    if (c < 15) {
      const int lon = dir ? (480 - 32 * (c + 1)) : (32 * (c + 1));
      const float4* g4 = (const float4*)(gi + (size_t)lon * 768);
      #pragma unroll
      for (int j = 0; j < 6; ++j) {
        const int f = j * 512 + tid;
        const int row = f / 96;
        const int col = f - row * 96;
        stg[j] = g4[row * 192 + col];
      }
    }

    for (int i = 0; i < 32; ++i) {
      const int sloc = dir ? (31 - i) : i;    // row within chunk
      const int seq = lo + sloc;              // absolute sequence index

      float4 A0 = {0.f, 0.f, 0.f, 0.f};
      float4 A1 = {0.f, 0.f, 0.f, 0.f};
      float4 A2 = {0.f, 0.f, 0.f, 0.f};
      #pragma unroll
      for (int kk = 0; kk < 8; ++kk) {
        const float4 hv = h4q[kk];              // broadcast b128 -> 12 FMA
        A0.x = fmaf(w0[kk].x, hv.x, A0.x);
        A0.y = fmaf(w0[kk].y, hv.y, A0.y);
        A0.z = fmaf(w0[kk].z, hv.z, A0.z);
        A0.w = fmaf(w0[kk].w, hv.w, A0.w);
        A1.x = fmaf(w1[kk].x, hv.x, A1.x);
        A1.y = fmaf(w1[kk].y, hv.y, A1.y);
        A1.z = fmaf(w1[kk].z, hv.z, A1.z);
        A1.w = fmaf(w1[kk].w, hv.w, A1.w);
        A2.x = fmaf(w2[kk].x, hv.x, A2.x);
        A2.y = fmaf(w2[kk].y, hv.y, A2.y);
        A2.z = fmaf(w2[kk].z, hv.z, A2.z);
        A2.w = fmaf(w2[kk].w, hv.w, A2.w);
      }
      partl[kq * 384 + r0]       = (A0.x + A0.y) + (A0.z + A0.w) + bh0;
      partl[kq * 384 + r0 + 64]  = (A1.x + A1.y) + (A1.z + A1.w) + bh1;
      partl[kq * 384 + r0 + 128] = (A2.x + A2.y) + (A2.z + A2.w) + bh2;
      LDS_BARRIER();

      if (tid < 128) {
        const float* grow = &gis[buf][sloc * 384];
        const float ghr = (partl[tid]       + partl[384 + tid])
                        + (partl[768 + tid] + partl[1152 + tid]);
        const float ghz = (partl[tid + 128]        + partl[384 + tid + 128])
                        + (partl[768 + tid + 128]  + partl[1152 + tid + 128]);
        const float ghn = (partl[tid + 256]        + partl[384 + tid + 256])
                        + (partl[768 + tid + 256]  + partl[1152 + tid + 256]);
        const float gir = grow[tid];
        const float giz = grow[tid + 128];
        const float gin = grow[tid + 256];
        const float r = __fdividef(1.f, 1.f + __expf(-(gir + ghr)));
        const float z = __fdividef(1.f, 1.f + __expf(-(giz + ghz)));
        float an = gin + r * ghn;
        an = fminf(fmaxf(an, -15.f), 15.f);
        const float t = __expf(2.f * an);
        const float n = __fdividef(t - 1.f, t + 1.f);
        hreg = (1.f - z) * n + z * hreg;
        hlds[tid] = hreg;
        srep[((size_t)(b * 512 + seq)) * 256 + dir * 128 + tid] = hreg;
      }
      LDS_BARRIER();
    }

    // write staged next chunk into the buffer we just finished reading
    if (c < 15) {
      float4* l4 = (float4*)gis[buf ^ 1];
      #pragma unroll
      for (int j = 0; j < 6; ++j) l4[j * 512 + tid] = stg[j];
      LDS_BARRIER();
    }
  }
  if (tid < 128) hfin[(size_t)dir * 4096 + (size_t)b * 128 + tid] = hreg;
}

// ---------------------------------------------------------------------------
// K4: topic boundary diffs.  grid = B*T = 512, 256 threads.
// ---------------------------------------------------------------------------
__global__ __launch_bounds__(256) void k_topic(
    const int* __restrict__ starts, const int* __restrict__ ends,
    const float* __restrict__ srep, float* __restrict__ tmat)
{
  const int bt = blockIdx.x;
  const int b = bt >> 4;
  const int st = starts[bt], en = ends[bt];
  const int j = threadIdx.x;
  float v;
  if (j < 128) {
    const float a = (en >= 1 && en <= 512) ? srep[((size_t)(b * 512 + en - 1)) * 256 + j] : 0.f;
    const float c = (st - 1 >= 1 && st - 1 <= 512) ? srep[((size_t)(b * 512 + st - 2)) * 256 + j] : 0.f;
    v = a - c;
  } else {
    const float a = (st >= 1 && st <= 512) ? srep[((size_t)(b * 512 + st - 1)) * 256 + j] : 0.f;
    const float c = (en + 1 >= 1 && en + 1 <= 512) ? srep[((size_t)(b * 512 + en)) * 256 + j] : 0.f;
    v = a - c;
  }
  tmat[(size_t)bt * 256 + j] = v;
}

// ---------------------------------------------------------------------------
// K6: attention scores + context + assemble decoder input.  grid = B*S.
// ---------------------------------------------------------------------------
__global__ __launch_bounds__(256) void k_scores(
    const float* spart, const float* __restrict__ docp, const float* __restrict__ topp,
    const float* __restrict__ v_att, const float* __restrict__ srep,
    const float* __restrict__ docrep, const float* __restrict__ tmat,
    const int* __restrict__ s2t, float* inp)
{
  const int bs = blockIdx.x;
  const int b = bs >> 9;
  const int tid = threadIdx.x;
  const int tp = s2t[bs];
  const float* sp = spart + (size_t)bs * 512;
  const float* dp = docp + (size_t)b * 512;
  const float* tq = topp + ((size_t)(b * 16 + tp)) * 512;
  float ds = 0.f, ts = 0.f;
  #pragma unroll
  for (int r = 0; r < 2; ++r) {
    const int o = tid + r * 256;
    const float s0 = sp[o], v = v_att[o];
    ds += tanhf(s0 + dp[o]) * v;
    ts += tanhf(s0 + tq[o]) * v;
  }
  #pragma unroll
  for (int off = 32; off; off >>= 1) {
    ds += __shfl_down(ds, off);
    ts += __shfl_down(ts, off);
  }
  __shared__ float rds[4], rts[4], wsh[2];
  const int wv = tid >> 6, ln = tid & 63;
  if (ln == 0) { rds[wv] = ds; rts[wv] = ts; }
  __syncthreads();
  if (tid == 0) {
    const float D = rds[0] + rds[1] + rds[2] + rds[3];
    const float T = rts[0] + rts[1] + rts[2] + rts[3];
    const float sum = D + T;
    wsh[0] = D / sum;
    wsh[1] = T / sum;
  }
  __syncthreads();
  const float dw = wsh[0], tw = wsh[1];
  const float sr = srep[(size_t)bs * 256 + tid];
  const float ctx = dw * docrep[(size_t)b * 256 + tid]
                  + tw * tmat[((size_t)(b * 16 + tp)) * 256 + tid];
  float* op = inp + (size_t)bs * 512;
  op[tid] = sr;
  op[256 + tid] = ctx;
}

// ---------------------------------------------------------------------------
// K8: logits[bs] = dot(hbuf[bs], W2) + b2.  grid = B*S, 64 threads.
// ---------------------------------------------------------------------------
__global__ __launch_bounds__(64) void k_logits(
    const float* __restrict__ hbuf, const float* __restrict__ W2,
    const float* __restrict__ b2, float* __restrict__ out)
{
  const int bs = blockIdx.x;
  const int ln = threadIdx.x;
  const float* h = hbuf + (size_t)bs * 128;
  float a = fmaf(h[ln], W2[ln], h[ln + 64] * W2[ln + 64]);
  #pragma unroll
  for (int off = 32; off; off >>= 1) a += __shfl_down(a, off);
  if (ln == 0) out[bs] = a + b2[0];
}

// ---------------------------------------------------------------------------
extern "C" void kernel_launch(void* const* d_in, const int* in_sizes, int n_in,
                              void* d_out, int out_size, void* d_ws, size_t ws_size,
                              hipStream_t stream)
{
  (void)in_sizes; (void)n_in; (void)out_size;

  const int*   word_ids = (const int*)d_in[0];
  const int*   starts   = (const int*)d_in[1];
  const int*   ends     = (const int*)d_in[2];
  const int*   s2t      = (const int*)d_in[3];
  const float* emb      = (const float*)d_in[4];
  const float* Wi_f     = (const float*)d_in[5];
  const float* Wh_f     = (const float*)d_in[6];
  const float* bi_f     = (const float*)d_in[7];
  const float* bh_f     = (const float*)d_in[8];
  const float* Wi_b     = (const float*)d_in[9];
  const float* Wh_b     = (const float*)d_in[10];
  const float* bi_b     = (const float*)d_in[11];
  const float* bh_b     = (const float*)d_in[12];
  const float* W_att    = (const float*)d_in[13];
  const float* v_att    = (const float*)d_in[14];
  const float* W1       = (const float*)d_in[15];
  const float* b1       = (const float*)d_in[16];
  const float* W2       = (const float*)d_in[17];
  const float* b2       = (const float*)d_in[18];
  float* out = (float*)d_out;

  // Workspace layout (bytes).  Aliasing:
  //   gi_fb (50.3MB) at +19,660,800; spart/inp (33.6MB) overlays it after k_gru
  //   Wcat/bcat (922KB) live at srep's start, dead before k_gru writes srep
  //   hbuf (8.4MB) overlays sent (dead after gi GEMM)
  char* ws = (char*)d_ws;
  if (ws_size < 88440832u) return;   // insufficient scratch -> fail loudly
  float* sent  = (float*)(ws + 0);          // 16384*300*4 = 19,660,800
  float* gi_fb = (float*)(ws + 19660800);   // 16384*768*4 = 50,331,648
  float* srep  = (float*)(ws + 69992448);   // 16384*256*4 = 16,777,216
  float* hfin  = (float*)(ws + 86769664);   // 2*32*128*4  = 32,768  (== doc_rep flat)
  float* tmat  = (float*)(ws + 86802432);   // 32*16*256*4 = 524,288
  float* docp  = (float*)(ws + 87326720);   // 32*512*4    = 65,536
  float* topp  = (float*)(ws + 87392256);   // 512*512*4   = 1,048,576 -> end 88,440,832
  float* spart = (float*)(ws + 19660800);   // alias gi_fb
  float* hbuf  = (float*)(ws + 0);          // alias sent
  float* Wcat  = (float*)(ws + 69992448);   // alias srep head (768*300*4 = 921,600)
  float* bcat  = (float*)(ws + 70914048);   // 768*4, still inside srep region

  // 1) sentence means (float4 gather)
  k_sent_mean<<<16384, 128, 0, stream>>>(word_ids, emb, sent);
  // 1b) concat input-gate weights/biases into ws
  k_wcat<<<450, 256, 0, stream>>>(Wi_f, Wi_b, bi_f, bi_b, Wcat, bcat);
  // 2) fused input gates: gi_fb = sent @ Wcat^T + bcat  (N=768)
  k_gemm<true, 0><<<dim3(256, 12), 256, 0, stream>>>(16384, 768, 300, sent, 300, Wcat, 300, gi_fb, 768, bcat);
  // 3) bidirectional GRU recurrence -> sent_rep (B,S,2H), hfin (2,B,H)
  k_gru<<<64, 512, 0, stream>>>(gi_fb, Wh_f, Wh_b, bh_f, bh_b, srep, hfin);
  // 4) topic boundary matrix
  k_topic<<<512, 256, 0, stream>>>(starts, ends, srep, tmat);
  // 5) attention partial projections (cat@W_att split by halves of W_att rows)
  k_gemm<false, 0><<<dim3(256, 8), 256, 0, stream>>>(16384, 512, 256, srep, 256, W_att + 256 * 512, 512, spart, 512, nullptr);
  k_gemm<false, 0><<<dim3(1, 8),   256, 0, stream>>>(32,    512, 256, hfin, 256, W_att,            512, docp,  512, nullptr);
  k_gemm<false, 0><<<dim3(8, 8),   256, 0, stream>>>(512,   512, 256, tmat, 256, W_att,            512, topp,  512, nullptr);
  // 6) scores -> weights -> context -> decoder input (in-place over spart)
  k_scores<<<16384, 256, 0, stream>>>(spart, docp, topp, v_att, srep, hfin, tmat, s2t, spart);
  // 7) h = relu(inp @ W1^T + b1)
  k_gemm<true, 1><<<dim3(256, 2), 256, 0, stream>>>(16384, 128, 512, spart, 512, W1, 512, hbuf, 128, b1);
  // 8) logits
  k_logits<<<16384, 64, 0, stream>>>(hbuf, W2, b2, out);
}